// Round 1
// baseline (1020.062 us; speedup 1.0000x reference)
//
#include <hip/hip_runtime.h>

#define NNODES 100000
#define NEDGES 1600000
#define DIM    128
#define OUTD   32
#define NGRAPH 512

// ============================================================
// GEMM: C[M,128] = epilogue(A[M,128] @ W[128,128])
// MODE 0: relu(acc + bias[col])
// MODE 1: acc * scale[row]          (GCN: fold inv_sqrt into rows)
// ============================================================
template<int MODE>
__global__ __launch_bounds__(256) void gemm128(
    const float* __restrict__ A, const float* __restrict__ W,
    const float* __restrict__ bias, const float* __restrict__ scale,
    float* __restrict__ C, int M)
{
    __shared__ float As[16][132];   // [k][m], padded to 132 (16B-aligned rows)
    __shared__ float Bs[16][132];   // [k][n]

    const int tid = threadIdx.x;
    const int m0  = blockIdx.x * 128;
    const int tx  = tid & 15;       // 0..15 -> col group
    const int ty  = tid >> 4;       // 0..15 -> row group

    const int ar = tid >> 2;              // 0..63  A tile row
    const int ac = (tid & 3) << 2;        // 0,4,8,12 (k offset)
    const int br = tid >> 5;              // 0..7   B tile k-row
    const int bc = (tid & 31) << 2;       // 0..124

    float acc[8][8];
    #pragma unroll
    for (int i = 0; i < 8; ++i)
        #pragma unroll
        for (int j = 0; j < 8; ++j) acc[i][j] = 0.f;

    for (int kt = 0; kt < 8; ++kt) {
        const int k0 = kt << 4;
        const int r0 = min(m0 + ar,      M - 1);
        const int r1 = min(m0 + ar + 64, M - 1);
        float4 a0 = *(const float4*)(A + (size_t)r0 * DIM + k0 + ac);
        float4 a1 = *(const float4*)(A + (size_t)r1 * DIM + k0 + ac);
        float4 b0 = *(const float4*)(W + (size_t)(k0 + br)     * DIM + bc);
        float4 b1 = *(const float4*)(W + (size_t)(k0 + br + 8) * DIM + bc);

        __syncthreads();
        As[ac + 0][ar] = a0.x; As[ac + 1][ar] = a0.y;
        As[ac + 2][ar] = a0.z; As[ac + 3][ar] = a0.w;
        As[ac + 0][ar + 64] = a1.x; As[ac + 1][ar + 64] = a1.y;
        As[ac + 2][ar + 64] = a1.z; As[ac + 3][ar + 64] = a1.w;
        *(float4*)&Bs[br][bc]     = b0;
        *(float4*)&Bs[br + 8][bc] = b1;
        __syncthreads();

        #pragma unroll
        for (int kk = 0; kk < 16; ++kk) {
            float4 fa0 = *(const float4*)&As[kk][ty * 8];
            float4 fa1 = *(const float4*)&As[kk][ty * 8 + 4];
            float4 fb0 = *(const float4*)&Bs[kk][tx * 8];
            float4 fb1 = *(const float4*)&Bs[kk][tx * 8 + 4];
            float av[8] = {fa0.x, fa0.y, fa0.z, fa0.w, fa1.x, fa1.y, fa1.z, fa1.w};
            float bv[8] = {fb0.x, fb0.y, fb0.z, fb0.w, fb1.x, fb1.y, fb1.z, fb1.w};
            #pragma unroll
            for (int i = 0; i < 8; ++i)
                #pragma unroll
                for (int j = 0; j < 8; ++j)
                    acc[i][j] = fmaf(av[i], bv[j], acc[i][j]);
        }
    }

    float bcol[8];
    if (MODE == 0) {
        float4 bb0 = *(const float4*)(bias + tx * 8);
        float4 bb1 = *(const float4*)(bias + tx * 8 + 4);
        bcol[0]=bb0.x; bcol[1]=bb0.y; bcol[2]=bb0.z; bcol[3]=bb0.w;
        bcol[4]=bb1.x; bcol[5]=bb1.y; bcol[6]=bb1.z; bcol[7]=bb1.w;
    }

    #pragma unroll
    for (int i = 0; i < 8; ++i) {
        const int r = m0 + ty * 8 + i;
        if (r >= M) break;
        float v[8];
        if (MODE == 0) {
            #pragma unroll
            for (int j = 0; j < 8; ++j) v[j] = fmaxf(acc[i][j] + bcol[j], 0.f);
        } else {
            const float s = scale[r];
            #pragma unroll
            for (int j = 0; j < 8; ++j) v[j] = acc[i][j] * s;
        }
        float4 o0 = make_float4(v[0], v[1], v[2], v[3]);
        float4 o1 = make_float4(v[4], v[5], v[6], v[7]);
        *(float4*)(C + (size_t)r * DIM + tx * 8)     = o0;
        *(float4*)(C + (size_t)r * DIM + tx * 8 + 4) = o1;
    }
}

// ============================================================
// CSR construction
// ============================================================
__global__ void k_zero_int(int* __restrict__ p, int n) {
    int i = blockIdx.x * 256 + threadIdx.x;
    if (i < n) p[i] = 0;
}

__global__ void k_count(const int* __restrict__ dst, int* __restrict__ cnt) {
    int e = blockIdx.x * 256 + threadIdx.x;
    if (e < NEDGES) atomicAdd(&cnt[dst[e]], 1);
}

__global__ void k_invsqrt(const int* __restrict__ cnt, float* __restrict__ inv) {
    int i = blockIdx.x * 256 + threadIdx.x;
    if (i < NNODES) inv[i] = rsqrtf((float)cnt[i] + 1.0f);
}

__global__ void k_scan1(const int* __restrict__ cnt, int* __restrict__ scan1,
                        int* __restrict__ bsum, int n) {
    __shared__ int s[256];
    int i = blockIdx.x * 256 + threadIdx.x;
    int v = (i < n) ? cnt[i] : 0;
    s[threadIdx.x] = v;
    __syncthreads();
    for (int off = 1; off < 256; off <<= 1) {
        int t = 0;
        if (threadIdx.x >= off) t = s[threadIdx.x - off];
        __syncthreads();
        s[threadIdx.x] += t;
        __syncthreads();
    }
    if (i < n) scan1[i] = s[threadIdx.x];
    if (threadIdx.x == 255) bsum[blockIdx.x] = s[255];
}

__global__ void k_scan2(int* __restrict__ bsum, int nb) {  // single block, 512 thr
    __shared__ int s[512];
    int v = (threadIdx.x < nb) ? bsum[threadIdx.x] : 0;
    s[threadIdx.x] = v;
    __syncthreads();
    for (int off = 1; off < 512; off <<= 1) {
        int t = 0;
        if (threadIdx.x >= off) t = s[threadIdx.x - off];
        __syncthreads();
        s[threadIdx.x] += t;
        __syncthreads();
    }
    if (threadIdx.x < nb) bsum[threadIdx.x] = s[threadIdx.x] - v;  // exclusive
}

__global__ void k_scan3(const int* __restrict__ scan1, const int* __restrict__ bsum,
                        int* __restrict__ row_off, int* __restrict__ cursor, int n) {
    int i = blockIdx.x * 256 + threadIdx.x;
    if (i < n) {
        int ro = scan1[i] + bsum[i >> 8];
        row_off[i + 1] = ro;
        cursor[i + 1]  = ro;
        if (i == 0) { row_off[0] = 0; cursor[0] = 0; }
    }
}

__global__ void k_fill(const int* __restrict__ src, const int* __restrict__ dst,
                       int* __restrict__ cursor, int* __restrict__ col) {
    int e = blockIdx.x * 256 + threadIdx.x;
    if (e < NEDGES) {
        int d = dst[e];
        int pos = atomicAdd(&cursor[d], 1);
        col[pos] = src[e];
    }
}

// ============================================================
// Aggregation: h_out[n] = relu(inv[n]*(hw'[n] + sum_in hw'[src]) + bias)
// one wave per node, float2 per lane
// ============================================================
__global__ __launch_bounds__(256) void k_agg(
    const float* __restrict__ hwp, const int* __restrict__ row_off,
    const int* __restrict__ col, const float* __restrict__ inv,
    const float* __restrict__ bias, float* __restrict__ hout)
{
    const int node = blockIdx.x * 4 + (threadIdx.x >> 6);
    const int lane = threadIdx.x & 63;
    if (node >= NNODES) return;

    const float2* hp = (const float2*)hwp;
    float2 acc = hp[(size_t)node * 64 + lane];   // self loop term
    const int s = row_off[node], e = row_off[node + 1];
    int j = s;
    for (; j + 1 < e; j += 2) {
        int u0 = col[j], u1 = col[j + 1];
        float2 v0 = hp[(size_t)u0 * 64 + lane];
        float2 v1 = hp[(size_t)u1 * 64 + lane];
        acc.x += v0.x + v1.x;
        acc.y += v0.y + v1.y;
    }
    if (j < e) {
        int u = col[j];
        float2 v = hp[(size_t)u * 64 + lane];
        acc.x += v.x; acc.y += v.y;
    }
    const float sc = inv[node];
    const float2 b = ((const float2*)bias)[lane];
    float2 o;
    o.x = fmaxf(fmaf(acc.x, sc, b.x), 0.f);
    o.y = fmaxf(fmaf(acc.y, sc, b.y), 0.f);
    ((float2*)hout)[(size_t)node * 64 + lane] = o;
}

// ============================================================
// Global add pool: batch is sorted; one block per graph
// ============================================================
__device__ int lbound(const int* __restrict__ a, int n, int v) {
    int lo = 0, hi = n;
    while (lo < hi) { int mid = (lo + hi) >> 1; if (a[mid] < v) lo = mid + 1; else hi = mid; }
    return lo;
}

__global__ __launch_bounds__(128) void k_pool(
    const float* __restrict__ h, const int* __restrict__ batch,
    float* __restrict__ pooled)
{
    __shared__ int se[2];
    const int g = blockIdx.x;
    if (threadIdx.x == 0) se[0] = lbound(batch, NNODES, g);
    if (threadIdx.x == 1) se[1] = lbound(batch, NNODES, g + 1);
    __syncthreads();
    const int s = se[0], e = se[1];
    const int f = threadIdx.x;
    float acc = 0.f;
    for (int n = s; n < e; ++n) acc += h[(size_t)n * DIM + f];
    pooled[(size_t)g * DIM + f] = acc;
}

// ============================================================
// Decoder layer 2: out[512,32] = t1[512,128] @ W2[128,32] + b2
// ============================================================
__global__ __launch_bounds__(256) void k_dec2(
    const float* __restrict__ t1, const float* __restrict__ W2,
    const float* __restrict__ b2, float* __restrict__ out)
{
    int idx = blockIdx.x * 256 + threadIdx.x;
    if (idx >= NGRAPH * OUTD) return;
    int r = idx >> 5, c = idx & 31;
    float acc = b2[c];
    #pragma unroll 8
    for (int k = 0; k < DIM; ++k)
        acc = fmaf(t1[(size_t)r * DIM + k], W2[(size_t)k * OUTD + c], acc);
    out[idx] = acc;
}

// ============================================================
extern "C" void kernel_launch(void* const* d_in, const int* in_sizes, int n_in,
                              void* d_out, int out_size, void* d_ws, size_t ws_size,
                              hipStream_t stream)
{
    const float* x      = (const float*)d_in[0];
    const int*   ei     = (const int*)d_in[1];
    const int*   batch  = (const int*)d_in[2];
    const float* enc_W1 = (const float*)d_in[3];
    const float* enc_b1 = (const float*)d_in[4];
    const float* enc_W2 = (const float*)d_in[5];
    const float* enc_b2 = (const float*)d_in[6];
    const float* gcn_W  = (const float*)d_in[7];
    const float* gcn_b  = (const float*)d_in[8];
    const float* dec_W1 = (const float*)d_in[9];
    const float* dec_b1 = (const float*)d_in[10];
    const float* dec_W2 = (const float*)d_in[11];
    const float* dec_b2 = (const float*)d_in[12];
    float* out = (float*)d_out;

    const int* src = ei;
    const int* dst = ei + NEDGES;

    // ---- workspace carve-up ----
    char* p = (char*)d_ws;
    auto alloc = [&](size_t bytes) -> void* {
        void* r = (void*)p;
        p += (bytes + 255) & ~(size_t)255;
        return r;
    };
    float* bufA    = (float*)alloc((size_t)NNODES * DIM * sizeof(float));
    float* bufB    = (float*)alloc((size_t)NNODES * DIM * sizeof(float));
    int*   cnt     = (int*)  alloc((size_t)NNODES * sizeof(int));
    float* inv     = (float*)alloc((size_t)NNODES * sizeof(float));
    int*   row_off = (int*)  alloc((size_t)(NNODES + 1) * sizeof(int));
    int*   cursor  = (int*)  alloc((size_t)(NNODES + 1) * sizeof(int));
    int*   scan1   = (int*)  alloc((size_t)NNODES * sizeof(int));
    int*   bsum    = (int*)  alloc(512 * sizeof(int));
    int*   col     = (int*)  alloc((size_t)NEDGES * sizeof(int));
    float* pooled  = (float*)alloc((size_t)NGRAPH * DIM * sizeof(float));
    float* t1      = (float*)alloc((size_t)NGRAPH * DIM * sizeof(float));

    const int nodeBlocks = (NNODES + 255) / 256;          // 391
    const int edgeBlocks = (NEDGES + 255) / 256;          // 6250
    const int gemmBlocks = (NNODES + 127) / 128;          // 782

    // ---- CSR build ----
    k_zero_int<<<nodeBlocks, 256, 0, stream>>>(cnt, NNODES);
    k_count  <<<edgeBlocks, 256, 0, stream>>>(dst, cnt);
    k_invsqrt<<<nodeBlocks, 256, 0, stream>>>(cnt, inv);
    k_scan1  <<<nodeBlocks, 256, 0, stream>>>(cnt, scan1, bsum, NNODES);
    k_scan2  <<<1, 512, 0, stream>>>(bsum, nodeBlocks);
    k_scan3  <<<nodeBlocks, 256, 0, stream>>>(scan1, bsum, row_off, cursor, NNODES);
    k_fill   <<<edgeBlocks, 256, 0, stream>>>(src, dst, cursor, col);

    // ---- encoder ----
    gemm128<0><<<gemmBlocks, 256, 0, stream>>>(x,    enc_W1, enc_b1, nullptr, bufA, NNODES);
    gemm128<0><<<gemmBlocks, 256, 0, stream>>>(bufA, enc_W2, enc_b2, nullptr, bufB, NNODES);

    // ---- GCN layers (h in bufB; hw' in bufA) ----
    for (int l = 0; l < 3; ++l) {
        gemm128<1><<<gemmBlocks, 256, 0, stream>>>(bufB, gcn_W + (size_t)l * DIM * DIM,
                                                   nullptr, inv, bufA, NNODES);
        k_agg<<<NNODES / 4, 256, 0, stream>>>(bufA, row_off, col, inv,
                                              gcn_b + (size_t)l * DIM, bufB);
    }

    // ---- pool + decoder ----
    k_pool<<<NGRAPH, 128, 0, stream>>>(bufB, batch, pooled);
    gemm128<0><<<(NGRAPH + 127) / 128, 256, 0, stream>>>(pooled, dec_W1, dec_b1, nullptr, t1, NGRAPH);
    k_dec2<<<(NGRAPH * OUTD + 255) / 256, 256, 0, stream>>>(t1, dec_W2, dec_b2, out);
}

// Round 2
// 767.064 us; speedup vs baseline: 1.3298x; 1.3298x over previous
//
#include <hip/hip_runtime.h>

#define NNODES 100000
#define NEDGES 1600000
#define DIM    128
#define OUTD   32
#define NGRAPH 512
#define LDA    136   // padded LDS stride (bf16 elems): +8 keeps 16B align, kills conflicts

using bf16x8 = __attribute__((ext_vector_type(8))) short;
using f32x4  = __attribute__((ext_vector_type(4))) float;

__device__ __forceinline__ short f2bf(float f) {
    unsigned u = __float_as_uint(f);
    unsigned r = (u + 0x7fff + ((u >> 16) & 1)) >> 16;   // RNE
    return (short)r;
}
__device__ __forceinline__ float bf2f(short s) {
    return __uint_as_float(((unsigned)(unsigned short)s) << 16);
}
__device__ __forceinline__ float bf2f_lo(unsigned u) { return __uint_as_float(u << 16); }
__device__ __forceinline__ float bf2f_hi(unsigned u) { return __uint_as_float(u & 0xffff0000u); }

// ============================================================
// bf16 MFMA GEMM: C[M,128](bf16) = epi(A[M,128] @ W[128,128])
// MODE 0: relu(acc + bias[col]) ; MODE 1: acc * inv[row]
// AFP32: A is fp32 (converted during staging), else bf16
// ============================================================
template<int MODE, int AFP32>
__global__ __launch_bounds__(256) void gemm_mfma(
    const void* __restrict__ Av, const float* __restrict__ W,
    const float* __restrict__ bias, const float* __restrict__ inv,
    short* __restrict__ C, int M)
{
    __shared__ short As[128 * LDA];
    __shared__ short Bs[128 * LDA];

    const int tid = threadIdx.x;
    const int m0  = blockIdx.x * 128;

    // ---- stage A tile -> As[row][k] ----
    if (AFP32) {
        const float* A = (const float*)Av;
        #pragma unroll
        for (int i = 0; i < 8; ++i) {
            int idx = tid + i * 256;
            int row = idx >> 4, kg = (idx & 15) << 3;
            int r = min(m0 + row, M - 1);
            const float4* sp = (const float4*)(A + (size_t)r * DIM + kg);
            float4 f0 = sp[0], f1 = sp[1];
            short t8[8] = { f2bf(f0.x), f2bf(f0.y), f2bf(f0.z), f2bf(f0.w),
                            f2bf(f1.x), f2bf(f1.y), f2bf(f1.z), f2bf(f1.w) };
            *(bf16x8*)&As[row * LDA + kg] = *(bf16x8*)t8;
        }
    } else {
        const short* A = (const short*)Av;
        #pragma unroll
        for (int i = 0; i < 8; ++i) {
            int idx = tid + i * 256;
            int row = idx >> 4, kg = (idx & 15) << 3;
            int r = min(m0 + row, M - 1);
            *(bf16x8*)&As[row * LDA + kg] = *(const bf16x8*)(A + (size_t)r * DIM + kg);
        }
    }
    // ---- stage W^T -> Bs[n][k] (fp32 -> bf16, transposed) ----
    #pragma unroll
    for (int i = 0; i < 8; ++i) {
        int idx = tid + i * 256;             // 0..2047
        int k = idx >> 4, ng = (idx & 15) << 3;
        const float4* sp = (const float4*)(W + (size_t)k * DIM + ng);
        float4 f0 = sp[0], f1 = sp[1];
        short t8[8] = { f2bf(f0.x), f2bf(f0.y), f2bf(f0.z), f2bf(f0.w),
                        f2bf(f1.x), f2bf(f1.y), f2bf(f1.z), f2bf(f1.w) };
        #pragma unroll
        for (int j = 0; j < 8; ++j) Bs[(ng + j) * LDA + k] = t8[j];
    }
    __syncthreads();

    const int wave = tid >> 6, lane = tid & 63;
    const int ml = lane & 15, quad = lane >> 4;
    const int w32 = wave * 32;

    f32x4 acc[2][8] = {};
    #pragma unroll
    for (int kk = 0; kk < 4; ++kk) {
        const int k0 = kk * 32 + quad * 8;
        bf16x8 a0 = *(bf16x8*)&As[(w32 + ml) * LDA + k0];
        bf16x8 a1 = *(bf16x8*)&As[(w32 + 16 + ml) * LDA + k0];
        #pragma unroll
        for (int ni = 0; ni < 8; ++ni) {
            bf16x8 b = *(bf16x8*)&Bs[(ni * 16 + ml) * LDA + k0];
            acc[0][ni] = __builtin_amdgcn_mfma_f32_16x16x32_bf16(a0, b, acc[0][ni], 0, 0, 0);
            acc[1][ni] = __builtin_amdgcn_mfma_f32_16x16x32_bf16(a1, b, acc[1][ni], 0, 0, 0);
        }
    }
    __syncthreads();

    // ---- epilogue: acc -> bf16 via LDS (reuse As) for coalesced stores ----
    short* Cs = As;
    #pragma unroll
    for (int mi = 0; mi < 2; ++mi) {
        #pragma unroll
        for (int ni = 0; ni < 8; ++ni) {
            const int colc = ni * 16 + ml;
            #pragma unroll
            for (int r = 0; r < 4; ++r) {
                const int row = w32 + mi * 16 + quad * 4 + r;
                float v = acc[mi][ni][r];
                if (MODE == 0) {
                    v = fmaxf(v + bias[colc], 0.f);
                } else {
                    int gr = min(m0 + row, M - 1);
                    v *= inv[gr];
                }
                Cs[row * LDA + colc] = f2bf(v);
            }
        }
    }
    __syncthreads();
    #pragma unroll
    for (int i = 0; i < 8; ++i) {
        int idx = tid + i * 256;
        int row = idx >> 4, cg = (idx & 15) << 3;
        int gr = m0 + row;
        if (gr < M)
            *(bf16x8*)(C + (size_t)gr * DIM + cg) = *(bf16x8*)&Cs[row * LDA + cg];
    }
}

// ============================================================
// fp32 GEMM for the tiny decoder (M=512)
// ============================================================
__global__ __launch_bounds__(256) void gemm128_f32(
    const float* __restrict__ A, const float* __restrict__ W,
    const float* __restrict__ bias, float* __restrict__ C, int M)
{
    __shared__ float As[16][132];
    __shared__ float Bs[16][132];

    const int tid = threadIdx.x;
    const int m0  = blockIdx.x * 128;
    const int tx  = tid & 15;
    const int ty  = tid >> 4;
    const int ar = tid >> 2;
    const int ac = (tid & 3) << 2;
    const int br = tid >> 5;
    const int bc = (tid & 31) << 2;

    float acc[8][8];
    #pragma unroll
    for (int i = 0; i < 8; ++i)
        #pragma unroll
        for (int j = 0; j < 8; ++j) acc[i][j] = 0.f;

    for (int kt = 0; kt < 8; ++kt) {
        const int k0 = kt << 4;
        const int r0 = min(m0 + ar,      M - 1);
        const int r1 = min(m0 + ar + 64, M - 1);
        float4 a0 = *(const float4*)(A + (size_t)r0 * DIM + k0 + ac);
        float4 a1 = *(const float4*)(A + (size_t)r1 * DIM + k0 + ac);
        float4 b0 = *(const float4*)(W + (size_t)(k0 + br)     * DIM + bc);
        float4 b1 = *(const float4*)(W + (size_t)(k0 + br + 8) * DIM + bc);

        __syncthreads();
        As[ac + 0][ar] = a0.x; As[ac + 1][ar] = a0.y;
        As[ac + 2][ar] = a0.z; As[ac + 3][ar] = a0.w;
        As[ac + 0][ar + 64] = a1.x; As[ac + 1][ar + 64] = a1.y;
        As[ac + 2][ar + 64] = a1.z; As[ac + 3][ar + 64] = a1.w;
        *(float4*)&Bs[br][bc]     = b0;
        *(float4*)&Bs[br + 8][bc] = b1;
        __syncthreads();

        #pragma unroll
        for (int kk = 0; kk < 16; ++kk) {
            float4 fa0 = *(const float4*)&As[kk][ty * 8];
            float4 fa1 = *(const float4*)&As[kk][ty * 8 + 4];
            float4 fb0 = *(const float4*)&Bs[kk][tx * 8];
            float4 fb1 = *(const float4*)&Bs[kk][tx * 8 + 4];
            float av[8] = {fa0.x, fa0.y, fa0.z, fa0.w, fa1.x, fa1.y, fa1.z, fa1.w};
            float bv[8] = {fb0.x, fb0.y, fb0.z, fb0.w, fb1.x, fb1.y, fb1.z, fb1.w};
            #pragma unroll
            for (int i = 0; i < 8; ++i)
                #pragma unroll
                for (int j = 0; j < 8; ++j)
                    acc[i][j] = fmaf(av[i], bv[j], acc[i][j]);
        }
    }

    float4 bb0 = *(const float4*)(bias + tx * 8);
    float4 bb1 = *(const float4*)(bias + tx * 8 + 4);
    float bcol[8] = {bb0.x, bb0.y, bb0.z, bb0.w, bb1.x, bb1.y, bb1.z, bb1.w};

    #pragma unroll
    for (int i = 0; i < 8; ++i) {
        const int r = m0 + ty * 8 + i;
        if (r >= M) break;
        float v[8];
        #pragma unroll
        for (int j = 0; j < 8; ++j) v[j] = fmaxf(acc[i][j] + bcol[j], 0.f);
        *(float4*)(C + (size_t)r * DIM + tx * 8)     = make_float4(v[0], v[1], v[2], v[3]);
        *(float4*)(C + (size_t)r * DIM + tx * 8 + 4) = make_float4(v[4], v[5], v[6], v[7]);
    }
}

// ============================================================
// CSR construction
// ============================================================
__global__ void k_zero_int(int* __restrict__ p, int n) {
    int i = blockIdx.x * 256 + threadIdx.x;
    if (i < n) p[i] = 0;
}

#define ETHREADS 400128   // ceil(NEDGES/4) rounded to 256

__global__ void k_count(const int* __restrict__ dst, int* __restrict__ cnt) {
    int t = blockIdx.x * 256 + threadIdx.x;
    #pragma unroll
    for (int i = 0; i < 4; ++i) {
        int e = t + i * ETHREADS;
        if (e < NEDGES) atomicAdd(&cnt[dst[e]], 1);
    }
}

__global__ void k_invsqrt(const int* __restrict__ cnt, float* __restrict__ inv) {
    int i = blockIdx.x * 256 + threadIdx.x;
    if (i < NNODES) inv[i] = rsqrtf((float)cnt[i] + 1.0f);
}

__global__ void k_scan1(const int* __restrict__ cnt, int* __restrict__ scan1,
                        int* __restrict__ bsum, int n) {
    __shared__ int s[256];
    int i = blockIdx.x * 256 + threadIdx.x;
    int v = (i < n) ? cnt[i] : 0;
    s[threadIdx.x] = v;
    __syncthreads();
    for (int off = 1; off < 256; off <<= 1) {
        int t = 0;
        if (threadIdx.x >= off) t = s[threadIdx.x - off];
        __syncthreads();
        s[threadIdx.x] += t;
        __syncthreads();
    }
    if (i < n) scan1[i] = s[threadIdx.x];
    if (threadIdx.x == 255) bsum[blockIdx.x] = s[255];
}

__global__ void k_scan2(int* __restrict__ bsum, int nb) {
    __shared__ int s[512];
    int v = (threadIdx.x < nb) ? bsum[threadIdx.x] : 0;
    s[threadIdx.x] = v;
    __syncthreads();
    for (int off = 1; off < 512; off <<= 1) {
        int t = 0;
        if (threadIdx.x >= off) t = s[threadIdx.x - off];
        __syncthreads();
        s[threadIdx.x] += t;
        __syncthreads();
    }
    if (threadIdx.x < nb) bsum[threadIdx.x] = s[threadIdx.x] - v;
}

__global__ void k_scan3(const int* __restrict__ scan1, const int* __restrict__ bsum,
                        int* __restrict__ row_off, int* __restrict__ cursor, int n) {
    int i = blockIdx.x * 256 + threadIdx.x;
    if (i < n) {
        int ro = scan1[i] + bsum[i >> 8];
        row_off[i + 1] = ro;
        cursor[i + 1]  = ro;
        if (i == 0) { row_off[0] = 0; cursor[0] = 0; }
    }
}

__global__ void k_fill(const int* __restrict__ src, const int* __restrict__ dst,
                       int* __restrict__ cursor, int* __restrict__ col) {
    int t = blockIdx.x * 256 + threadIdx.x;
    #pragma unroll
    for (int i = 0; i < 4; ++i) {
        int e = t + i * ETHREADS;
        if (e < NEDGES) {
            int d = dst[e];
            int pos = atomicAdd(&cursor[d], 1);
            col[pos] = src[e];
        }
    }
}

// ============================================================
// Aggregation (bf16): h_out[n] = relu(inv[n]*(hw'[n] + sum hw'[src]) + b)
// one wave per node, 2 features (1 dword) per lane
// ============================================================
__global__ __launch_bounds__(256) void k_agg(
    const short* __restrict__ hwp, const int* __restrict__ row_off,
    const int* __restrict__ col, const float* __restrict__ inv,
    const float* __restrict__ bias, short* __restrict__ hout)
{
    const int node = blockIdx.x * 4 + (threadIdx.x >> 6);
    const int lane = threadIdx.x & 63;
    if (node >= NNODES) return;

    const unsigned* hp = (const unsigned*)hwp;
    unsigned us = hp[(size_t)node * 64 + lane];
    float ax = bf2f_lo(us), ay = bf2f_hi(us);

    const int s = row_off[node], e = row_off[node + 1];
    int j = s;
    for (; j + 3 < e; j += 4) {
        int u0 = col[j], u1 = col[j + 1], u2 = col[j + 2], u3 = col[j + 3];
        unsigned v0 = hp[(size_t)u0 * 64 + lane];
        unsigned v1 = hp[(size_t)u1 * 64 + lane];
        unsigned v2 = hp[(size_t)u2 * 64 + lane];
        unsigned v3 = hp[(size_t)u3 * 64 + lane];
        ax += bf2f_lo(v0) + bf2f_lo(v1) + bf2f_lo(v2) + bf2f_lo(v3);
        ay += bf2f_hi(v0) + bf2f_hi(v1) + bf2f_hi(v2) + bf2f_hi(v3);
    }
    for (; j < e; ++j) {
        unsigned v = hp[(size_t)col[j] * 64 + lane];
        ax += bf2f_lo(v); ay += bf2f_hi(v);
    }
    const float sc = inv[node];
    const float2 b = ((const float2*)bias)[lane];
    float ox = fmaxf(fmaf(ax, sc, b.x), 0.f);
    float oy = fmaxf(fmaf(ay, sc, b.y), 0.f);
    unsigned lo = (unsigned)(unsigned short)f2bf(ox);
    unsigned hi = (unsigned)(unsigned short)f2bf(oy);
    ((unsigned*)hout)[(size_t)node * 64 + lane] = lo | (hi << 16);
}

// ============================================================
// Global add pool (bf16 in, fp32 out)
// ============================================================
__device__ int lbound(const int* __restrict__ a, int n, int v) {
    int lo = 0, hi = n;
    while (lo < hi) { int mid = (lo + hi) >> 1; if (a[mid] < v) lo = mid + 1; else hi = mid; }
    return lo;
}

__global__ __launch_bounds__(128) void k_pool(
    const short* __restrict__ h, const int* __restrict__ batch,
    float* __restrict__ pooled)
{
    __shared__ int se[2];
    const int g = blockIdx.x;
    if (threadIdx.x == 0) se[0] = lbound(batch, NNODES, g);
    if (threadIdx.x == 1) se[1] = lbound(batch, NNODES, g + 1);
    __syncthreads();
    const int s = se[0], e = se[1];
    const int f = threadIdx.x;
    float acc = 0.f;
    for (int n = s; n < e; ++n) acc += bf2f(h[(size_t)n * DIM + f]);
    pooled[(size_t)g * DIM + f] = acc;
}

// ============================================================
__global__ __launch_bounds__(256) void k_dec2(
    const float* __restrict__ t1, const float* __restrict__ W2,
    const float* __restrict__ b2, float* __restrict__ out)
{
    int idx = blockIdx.x * 256 + threadIdx.x;
    if (idx >= NGRAPH * OUTD) return;
    int r = idx >> 5, c = idx & 31;
    float acc = b2[c];
    #pragma unroll 8
    for (int k = 0; k < DIM; ++k)
        acc = fmaf(t1[(size_t)r * DIM + k], W2[(size_t)k * OUTD + c], acc);
    out[idx] = acc;
}

// ============================================================
extern "C" void kernel_launch(void* const* d_in, const int* in_sizes, int n_in,
                              void* d_out, int out_size, void* d_ws, size_t ws_size,
                              hipStream_t stream)
{
    const float* x      = (const float*)d_in[0];
    const int*   ei     = (const int*)d_in[1];
    const int*   batch  = (const int*)d_in[2];
    const float* enc_W1 = (const float*)d_in[3];
    const float* enc_b1 = (const float*)d_in[4];
    const float* enc_W2 = (const float*)d_in[5];
    const float* enc_b2 = (const float*)d_in[6];
    const float* gcn_W  = (const float*)d_in[7];
    const float* gcn_b  = (const float*)d_in[8];
    const float* dec_W1 = (const float*)d_in[9];
    const float* dec_b1 = (const float*)d_in[10];
    const float* dec_W2 = (const float*)d_in[11];
    const float* dec_b2 = (const float*)d_in[12];
    float* out = (float*)d_out;

    const int* src = ei;
    const int* dst = ei + NEDGES;

    char* p = (char*)d_ws;
    auto alloc = [&](size_t bytes) -> void* {
        void* r = (void*)p;
        p += (bytes + 255) & ~(size_t)255;
        return r;
    };
    short* bufA    = (short*)alloc((size_t)NNODES * DIM * sizeof(short));
    short* bufB    = (short*)alloc((size_t)NNODES * DIM * sizeof(short));
    int*   cnt     = (int*)  alloc((size_t)NNODES * sizeof(int));
    float* inv     = (float*)alloc((size_t)NNODES * sizeof(float));
    int*   row_off = (int*)  alloc((size_t)(NNODES + 1) * sizeof(int));
    int*   cursor  = (int*)  alloc((size_t)(NNODES + 1) * sizeof(int));
    int*   scan1   = (int*)  alloc((size_t)NNODES * sizeof(int));
    int*   bsum    = (int*)  alloc(512 * sizeof(int));
    int*   col     = (int*)  alloc((size_t)NEDGES * sizeof(int));
    float* pooled  = (float*)alloc((size_t)NGRAPH * DIM * sizeof(float));
    float* t1      = (float*)alloc((size_t)NGRAPH * DIM * sizeof(float));

    const int nodeBlocks = (NNODES + 255) / 256;   // 391
    const int eBlocks4   = ETHREADS / 256;         // 1563
    const int gemmBlocks = (NNODES + 127) / 128;   // 782

    // ---- CSR build ----
    k_zero_int<<<nodeBlocks, 256, 0, stream>>>(cnt, NNODES);
    k_count  <<<eBlocks4, 256, 0, stream>>>(dst, cnt);
    k_invsqrt<<<nodeBlocks, 256, 0, stream>>>(cnt, inv);
    k_scan1  <<<nodeBlocks, 256, 0, stream>>>(cnt, scan1, bsum, NNODES);
    k_scan2  <<<1, 512, 0, stream>>>(bsum, nodeBlocks);
    k_scan3  <<<nodeBlocks, 256, 0, stream>>>(scan1, bsum, row_off, cursor, NNODES);
    k_fill   <<<eBlocks4, 256, 0, stream>>>(src, dst, cursor, col);

    // ---- encoder (fp32 x -> bf16 h) ----
    gemm_mfma<0,1><<<gemmBlocks, 256, 0, stream>>>(x,    enc_W1, enc_b1, nullptr, bufA, NNODES);
    gemm_mfma<0,0><<<gemmBlocks, 256, 0, stream>>>(bufA, enc_W2, enc_b2, nullptr, bufB, NNODES);

    // ---- GCN layers (h in bufB, hw' in bufA; all bf16) ----
    for (int l = 0; l < 3; ++l) {
        gemm_mfma<1,0><<<gemmBlocks, 256, 0, stream>>>(bufB, gcn_W + (size_t)l * DIM * DIM,
                                                       nullptr, inv, bufA, NNODES);
        k_agg<<<NNODES / 4, 256, 0, stream>>>(bufA, row_off, col, inv,
                                              gcn_b + (size_t)l * DIM, bufB);
    }

    // ---- pool + decoder (fp32) ----
    k_pool<<<NGRAPH, 128, 0, stream>>>(bufB, batch, pooled);
    gemm128_f32<<<(NGRAPH + 127) / 128, 256, 0, stream>>>(pooled, dec_W1, dec_b1, t1, NGRAPH);
    k_dec2<<<(NGRAPH * OUTD + 255) / 256, 256, 0, stream>>>(t1, dec_W2, dec_b2, out);
}

// Round 3
// 674.289 us; speedup vs baseline: 1.5128x; 1.1376x over previous
//
#include <hip/hip_runtime.h>

#define NNODES 100000
#define NEDGES 1600000
#define DIM    128
#define OUTD   32
#define NGRAPH 512
#define LDA    136   // padded LDS stride (bf16 elems)

#define NBUCK   1024          // coarse buckets: bucket = dst >> 7 (0..781 used)
#define NSETS   8             // one append-stream set per (hoped) XCD
#define EPB     4096          // edges per block in hist/scatter
#define EBLOCKS ((NEDGES + EPB - 1) / EPB)   // 391

using bf16x8 = __attribute__((ext_vector_type(8))) short;
using f32x4  = __attribute__((ext_vector_type(4))) float;

__device__ __forceinline__ short f2bf(float f) {
    unsigned u = __float_as_uint(f);
    unsigned r = (u + 0x7fff + ((u >> 16) & 1)) >> 16;   // RNE
    return (short)r;
}
__device__ __forceinline__ float bf2f(short s) {
    return __uint_as_float(((unsigned)(unsigned short)s) << 16);
}
__device__ __forceinline__ float bf2f_lo(unsigned u) { return __uint_as_float(u << 16); }
__device__ __forceinline__ float bf2f_hi(unsigned u) { return __uint_as_float(u & 0xffff0000u); }

// ============================================================
// bf16 MFMA GEMM: C[M,128](bf16) = epi(A[M,128] @ W[128,128])
// MODE 0: relu(acc + bias[col]) ; MODE 1: acc * inv[row]
// ============================================================
template<int MODE, int AFP32>
__global__ __launch_bounds__(256) void gemm_mfma(
    const void* __restrict__ Av, const float* __restrict__ W,
    const float* __restrict__ bias, const float* __restrict__ inv,
    short* __restrict__ C, int M)
{
    __shared__ short As[128 * LDA];
    __shared__ short Bs[128 * LDA];

    const int tid = threadIdx.x;
    const int m0  = blockIdx.x * 128;

    if (AFP32) {
        const float* A = (const float*)Av;
        #pragma unroll
        for (int i = 0; i < 8; ++i) {
            int idx = tid + i * 256;
            int row = idx >> 4, kg = (idx & 15) << 3;
            int r = min(m0 + row, M - 1);
            const float4* sp = (const float4*)(A + (size_t)r * DIM + kg);
            float4 f0 = sp[0], f1 = sp[1];
            short t8[8] = { f2bf(f0.x), f2bf(f0.y), f2bf(f0.z), f2bf(f0.w),
                            f2bf(f1.x), f2bf(f1.y), f2bf(f1.z), f2bf(f1.w) };
            *(bf16x8*)&As[row * LDA + kg] = *(bf16x8*)t8;
        }
    } else {
        const short* A = (const short*)Av;
        #pragma unroll
        for (int i = 0; i < 8; ++i) {
            int idx = tid + i * 256;
            int row = idx >> 4, kg = (idx & 15) << 3;
            int r = min(m0 + row, M - 1);
            *(bf16x8*)&As[row * LDA + kg] = *(const bf16x8*)(A + (size_t)r * DIM + kg);
        }
    }
    #pragma unroll
    for (int i = 0; i < 8; ++i) {
        int idx = tid + i * 256;
        int k = idx >> 4, ng = (idx & 15) << 3;
        const float4* sp = (const float4*)(W + (size_t)k * DIM + ng);
        float4 f0 = sp[0], f1 = sp[1];
        short t8[8] = { f2bf(f0.x), f2bf(f0.y), f2bf(f0.z), f2bf(f0.w),
                        f2bf(f1.x), f2bf(f1.y), f2bf(f1.z), f2bf(f1.w) };
        #pragma unroll
        for (int j = 0; j < 8; ++j) Bs[(ng + j) * LDA + k] = t8[j];
    }
    __syncthreads();

    const int wave = tid >> 6, lane = tid & 63;
    const int ml = lane & 15, quad = lane >> 4;
    const int w32 = wave * 32;

    f32x4 acc[2][8] = {};
    #pragma unroll
    for (int kk = 0; kk < 4; ++kk) {
        const int k0 = kk * 32 + quad * 8;
        bf16x8 a0 = *(bf16x8*)&As[(w32 + ml) * LDA + k0];
        bf16x8 a1 = *(bf16x8*)&As[(w32 + 16 + ml) * LDA + k0];
        #pragma unroll
        for (int ni = 0; ni < 8; ++ni) {
            bf16x8 b = *(bf16x8*)&Bs[(ni * 16 + ml) * LDA + k0];
            acc[0][ni] = __builtin_amdgcn_mfma_f32_16x16x32_bf16(a0, b, acc[0][ni], 0, 0, 0);
            acc[1][ni] = __builtin_amdgcn_mfma_f32_16x16x32_bf16(a1, b, acc[1][ni], 0, 0, 0);
        }
    }
    __syncthreads();

    short* Cs = As;
    #pragma unroll
    for (int mi = 0; mi < 2; ++mi) {
        #pragma unroll
        for (int ni = 0; ni < 8; ++ni) {
            const int colc = ni * 16 + ml;
            #pragma unroll
            for (int r = 0; r < 4; ++r) {
                const int row = w32 + mi * 16 + quad * 4 + r;
                float v = acc[mi][ni][r];
                if (MODE == 0) {
                    v = fmaxf(v + bias[colc], 0.f);
                } else {
                    int gr = min(m0 + row, M - 1);
                    v *= inv[gr];
                }
                Cs[row * LDA + colc] = f2bf(v);
            }
        }
    }
    __syncthreads();
    #pragma unroll
    for (int i = 0; i < 8; ++i) {
        int idx = tid + i * 256;
        int row = idx >> 4, cg = (idx & 15) << 3;
        int gr = m0 + row;
        if (gr < M)
            *(bf16x8*)(C + (size_t)gr * DIM + cg) = *(bf16x8*)&Cs[row * LDA + cg];
    }
}

// ============================================================
// fp32 GEMM for the tiny decoder (M=512)
// ============================================================
__global__ __launch_bounds__(256) void gemm128_f32(
    const float* __restrict__ A, const float* __restrict__ W,
    const float* __restrict__ bias, float* __restrict__ C, int M)
{
    __shared__ float As[16][132];
    __shared__ float Bs[16][132];

    const int tid = threadIdx.x;
    const int m0  = blockIdx.x * 128;
    const int tx  = tid & 15;
    const int ty  = tid >> 4;
    const int ar = tid >> 2;
    const int ac = (tid & 3) << 2;
    const int br = tid >> 5;
    const int bc = (tid & 31) << 2;

    float acc[8][8];
    #pragma unroll
    for (int i = 0; i < 8; ++i)
        #pragma unroll
        for (int j = 0; j < 8; ++j) acc[i][j] = 0.f;

    for (int kt = 0; kt < 8; ++kt) {
        const int k0 = kt << 4;
        const int r0 = min(m0 + ar,      M - 1);
        const int r1 = min(m0 + ar + 64, M - 1);
        float4 a0 = *(const float4*)(A + (size_t)r0 * DIM + k0 + ac);
        float4 a1 = *(const float4*)(A + (size_t)r1 * DIM + k0 + ac);
        float4 b0 = *(const float4*)(W + (size_t)(k0 + br)     * DIM + bc);
        float4 b1 = *(const float4*)(W + (size_t)(k0 + br + 8) * DIM + bc);

        __syncthreads();
        As[ac + 0][ar] = a0.x; As[ac + 1][ar] = a0.y;
        As[ac + 2][ar] = a0.z; As[ac + 3][ar] = a0.w;
        As[ac + 0][ar + 64] = a1.x; As[ac + 1][ar + 64] = a1.y;
        As[ac + 2][ar + 64] = a1.z; As[ac + 3][ar + 64] = a1.w;
        *(float4*)&Bs[br][bc]     = b0;
        *(float4*)&Bs[br + 8][bc] = b1;
        __syncthreads();

        #pragma unroll
        for (int kk = 0; kk < 16; ++kk) {
            float4 fa0 = *(const float4*)&As[kk][ty * 8];
            float4 fa1 = *(const float4*)&As[kk][ty * 8 + 4];
            float4 fb0 = *(const float4*)&Bs[kk][tx * 8];
            float4 fb1 = *(const float4*)&Bs[kk][tx * 8 + 4];
            float av[8] = {fa0.x, fa0.y, fa0.z, fa0.w, fa1.x, fa1.y, fa1.z, fa1.w};
            float bv[8] = {fb0.x, fb0.y, fb0.z, fb0.w, fb1.x, fb1.y, fb1.z, fb1.w};
            #pragma unroll
            for (int i = 0; i < 8; ++i)
                #pragma unroll
                for (int j = 0; j < 8; ++j)
                    acc[i][j] = fmaf(av[i], bv[j], acc[i][j]);
        }
    }

    float4 bb0 = *(const float4*)(bias + tx * 8);
    float4 bb1 = *(const float4*)(bias + tx * 8 + 4);
    float bcol[8] = {bb0.x, bb0.y, bb0.z, bb0.w, bb1.x, bb1.y, bb1.z, bb1.w};

    #pragma unroll
    for (int i = 0; i < 8; ++i) {
        const int r = m0 + ty * 8 + i;
        if (r >= M) break;
        float v[8];
        #pragma unroll
        for (int j = 0; j < 8; ++j) v[j] = fmaxf(acc[i][j] + bcol[j], 0.f);
        *(float4*)(C + (size_t)r * DIM + tx * 8)     = make_float4(v[0], v[1], v[2], v[3]);
        *(float4*)(C + (size_t)r * DIM + tx * 8 + 4) = make_float4(v[4], v[5], v[6], v[7]);
    }
}

// ============================================================
// Bucketed CSR build
// ============================================================
__global__ void k_zero_int(int* __restrict__ p, int n) {
    int i = blockIdx.x * 256 + threadIdx.x;
    if (i < n) p[i] = 0;
}

// per-(set,bucket) histogram via LDS
__global__ __launch_bounds__(256) void k_bhist(
    const int* __restrict__ dst, int* __restrict__ bcnt)
{
    __shared__ int h[NBUCK];
    const int tid = threadIdx.x;
    for (int i = tid; i < NBUCK; i += 256) h[i] = 0;
    __syncthreads();
    const int base = blockIdx.x * EPB;
    const int set  = blockIdx.x & (NSETS - 1);
    #pragma unroll
    for (int it = 0; it < EPB / 256; ++it) {
        int e = base + it * 256 + tid;
        if (e < NEDGES) atomicAdd(&h[dst[e] >> 7], 1);
    }
    __syncthreads();
    for (int i = tid; i < NBUCK; i += 256)
        if (h[i]) atomicAdd(&bcnt[set * NBUCK + i], h[i]);
}

// one block: scan 8192 (set-major) -> boff + cursors; scan 1024 bucket totals -> bbase
__global__ __launch_bounds__(1024) void k_bscan(
    const int* __restrict__ bcnt, int* __restrict__ boff,
    int* __restrict__ cur, int* __restrict__ bbase)
{
    __shared__ int s[1024];
    const int tid = threadIdx.x;
    // phase 1: exclusive scan over 8192 counts (idx = set*1024 + b)
    int v[8], pre[8], sum = 0;
    const int base = tid * 8;
    #pragma unroll
    for (int j = 0; j < 8; ++j) { v[j] = bcnt[base + j]; pre[j] = sum; sum += v[j]; }
    s[tid] = sum;
    __syncthreads();
    for (int off = 1; off < 1024; off <<= 1) {
        int t = (tid >= off) ? s[tid - off] : 0;
        __syncthreads();
        s[tid] += t;
        __syncthreads();
    }
    int excl = s[tid] - sum;
    #pragma unroll
    for (int j = 0; j < 8; ++j) {
        int o = excl + pre[j];
        boff[base + j] = o;
        cur[(base + j) << 4] = o;   // 64B-padded cursor
    }
    __syncthreads();
    // phase 2: node-major bucket bases
    int bt = 0;
    #pragma unroll
    for (int st = 0; st < NSETS; ++st) bt += bcnt[st * NBUCK + tid];
    s[tid] = bt;
    __syncthreads();
    for (int off = 1; off < 1024; off <<= 1) {
        int t = (tid >= off) ? s[tid - off] : 0;
        __syncthreads();
        s[tid] += t;
        __syncthreads();
    }
    bbase[tid] = s[tid] - bt;
}

// append (src | local<<17) into per-(set,bucket) region
__global__ __launch_bounds__(256) void k_bscatter(
    const int* __restrict__ src, const int* __restrict__ dst,
    int* __restrict__ cur, unsigned* __restrict__ tmp)
{
    const int tid  = threadIdx.x;
    const int base = blockIdx.x * EPB;
    const int set  = blockIdx.x & (NSETS - 1);
    #pragma unroll
    for (int it = 0; it < EPB / 256; ++it) {
        int e = base + it * 256 + tid;
        if (e < NEDGES) {
            int sv = src[e], d = dst[e];
            int b = d >> 7;
            int pos = atomicAdd(&cur[(set * NBUCK + b) << 4], 1);
            tmp[pos] = (unsigned)sv | ((unsigned)(d & 127) << 17);
        }
    }
}

// one block per bucket: per-node hist -> row_off/inv, then place col via LDS cursors
__global__ __launch_bounds__(256) void k_build(
    const unsigned* __restrict__ tmp, const int* __restrict__ bcnt,
    const int* __restrict__ boff, const int* __restrict__ bbase,
    int* __restrict__ row_off, float* __restrict__ inv, int* __restrict__ col)
{
    __shared__ int hist[128], sc[128], lcur[128];
    const int tid = threadIdx.x;
    const int b   = blockIdx.x;
    if (tid < 128) hist[tid] = 0;
    __syncthreads();
    #pragma unroll
    for (int st = 0; st < NSETS; ++st) {
        int idx = st * NBUCK + b;
        int s0 = boff[idx], n = bcnt[idx];
        for (int i = s0 + tid; i < s0 + n; i += 256)
            atomicAdd(&hist[(tmp[i] >> 17) & 127], 1);
    }
    __syncthreads();
    if (tid < 128) sc[tid] = hist[tid];
    __syncthreads();
    for (int off = 1; off < 128; off <<= 1) {
        int t = 0;
        if (tid < 128 && tid >= off) t = sc[tid - off];
        __syncthreads();
        if (tid < 128) sc[tid] += t;
        __syncthreads();
    }
    if (tid < 128) {
        const int node = b * 128 + tid;
        const int ro = bbase[b] + sc[tid] - hist[tid];
        if (node < NNODES) {
            row_off[node] = ro;
            inv[node] = rsqrtf((float)hist[tid] + 1.0f);
            if (node == NNODES - 1) row_off[NNODES] = ro + hist[tid];
        }
        lcur[tid] = ro;
    }
    __syncthreads();
    #pragma unroll
    for (int st = 0; st < NSETS; ++st) {
        int idx = st * NBUCK + b;
        int s0 = boff[idx], n = bcnt[idx];
        for (int i = s0 + tid; i < s0 + n; i += 256) {
            unsigned t = tmp[i];
            int pos = atomicAdd(&lcur[(t >> 17) & 127], 1);
            col[pos] = (int)(t & 0x1FFFFu);
        }
    }
}

// ============================================================
// Aggregation (bf16)
// ============================================================
__global__ __launch_bounds__(256) void k_agg(
    const short* __restrict__ hwp, const int* __restrict__ row_off,
    const int* __restrict__ col, const float* __restrict__ inv,
    const float* __restrict__ bias, short* __restrict__ hout)
{
    const int node = blockIdx.x * 4 + (threadIdx.x >> 6);
    const int lane = threadIdx.x & 63;
    if (node >= NNODES) return;

    const unsigned* hp = (const unsigned*)hwp;
    unsigned us = hp[(size_t)node * 64 + lane];
    float ax = bf2f_lo(us), ay = bf2f_hi(us);

    const int s = row_off[node], e = row_off[node + 1];
    int j = s;
    for (; j + 3 < e; j += 4) {
        int u0 = col[j], u1 = col[j + 1], u2 = col[j + 2], u3 = col[j + 3];
        unsigned v0 = hp[(size_t)u0 * 64 + lane];
        unsigned v1 = hp[(size_t)u1 * 64 + lane];
        unsigned v2 = hp[(size_t)u2 * 64 + lane];
        unsigned v3 = hp[(size_t)u3 * 64 + lane];
        ax += bf2f_lo(v0) + bf2f_lo(v1) + bf2f_lo(v2) + bf2f_lo(v3);
        ay += bf2f_hi(v0) + bf2f_hi(v1) + bf2f_hi(v2) + bf2f_hi(v3);
    }
    for (; j < e; ++j) {
        unsigned v = hp[(size_t)col[j] * 64 + lane];
        ax += bf2f_lo(v); ay += bf2f_hi(v);
    }
    const float sc = inv[node];
    const float2 b = ((const float2*)bias)[lane];
    float ox = fmaxf(fmaf(ax, sc, b.x), 0.f);
    float oy = fmaxf(fmaf(ay, sc, b.y), 0.f);
    unsigned lo = (unsigned)(unsigned short)f2bf(ox);
    unsigned hi = (unsigned)(unsigned short)f2bf(oy);
    ((unsigned*)hout)[(size_t)node * 64 + lane] = lo | (hi << 16);
}

// ============================================================
// Global add pool (bf16 in, fp32 out)
// ============================================================
__device__ int lbound(const int* __restrict__ a, int n, int v) {
    int lo = 0, hi = n;
    while (lo < hi) { int mid = (lo + hi) >> 1; if (a[mid] < v) lo = mid + 1; else hi = mid; }
    return lo;
}

__global__ __launch_bounds__(128) void k_pool(
    const short* __restrict__ h, const int* __restrict__ batch,
    float* __restrict__ pooled)
{
    __shared__ int se[2];
    const int g = blockIdx.x;
    if (threadIdx.x == 0) se[0] = lbound(batch, NNODES, g);
    if (threadIdx.x == 1) se[1] = lbound(batch, NNODES, g + 1);
    __syncthreads();
    const int s = se[0], e = se[1];
    const int f = threadIdx.x;
    float acc = 0.f;
    for (int n = s; n < e; ++n) acc += bf2f(h[(size_t)n * DIM + f]);
    pooled[(size_t)g * DIM + f] = acc;
}

// ============================================================
__global__ __launch_bounds__(256) void k_dec2(
    const float* __restrict__ t1, const float* __restrict__ W2,
    const float* __restrict__ b2, float* __restrict__ out)
{
    int idx = blockIdx.x * 256 + threadIdx.x;
    if (idx >= NGRAPH * OUTD) return;
    int r = idx >> 5, c = idx & 31;
    float acc = b2[c];
    #pragma unroll 8
    for (int k = 0; k < DIM; ++k)
        acc = fmaf(t1[(size_t)r * DIM + k], W2[(size_t)k * OUTD + c], acc);
    out[idx] = acc;
}

// ============================================================
extern "C" void kernel_launch(void* const* d_in, const int* in_sizes, int n_in,
                              void* d_out, int out_size, void* d_ws, size_t ws_size,
                              hipStream_t stream)
{
    const float* x      = (const float*)d_in[0];
    const int*   ei     = (const int*)d_in[1];
    const int*   batch  = (const int*)d_in[2];
    const float* enc_W1 = (const float*)d_in[3];
    const float* enc_b1 = (const float*)d_in[4];
    const float* enc_W2 = (const float*)d_in[5];
    const float* enc_b2 = (const float*)d_in[6];
    const float* gcn_W  = (const float*)d_in[7];
    const float* gcn_b  = (const float*)d_in[8];
    const float* dec_W1 = (const float*)d_in[9];
    const float* dec_b1 = (const float*)d_in[10];
    const float* dec_W2 = (const float*)d_in[11];
    const float* dec_b2 = (const float*)d_in[12];
    float* out = (float*)d_out;

    const int* src = ei;
    const int* dst = ei + NEDGES;

    char* p = (char*)d_ws;
    auto alloc = [&](size_t bytes) -> void* {
        void* r = (void*)p;
        p += (bytes + 255) & ~(size_t)255;
        return r;
    };
    short*    bufA   = (short*)   alloc((size_t)NNODES * DIM * sizeof(short));
    short*    bufB   = (short*)   alloc((size_t)NNODES * DIM * sizeof(short));
    float*    inv    = (float*)   alloc((size_t)NNODES * sizeof(float));
    int*      row_off= (int*)     alloc((size_t)(NNODES + 1) * sizeof(int));
    int*      col    = (int*)     alloc((size_t)NEDGES * sizeof(int));
    unsigned* tmp    = (unsigned*)alloc((size_t)NEDGES * sizeof(unsigned));
    int*      bcnt   = (int*)     alloc((size_t)NSETS * NBUCK * sizeof(int));
    int*      boff   = (int*)     alloc((size_t)NSETS * NBUCK * sizeof(int));
    int*      bbase  = (int*)     alloc((size_t)NBUCK * sizeof(int));
    int*      cur    = (int*)     alloc((size_t)NSETS * NBUCK * 16 * sizeof(int));
    float*    pooled = (float*)   alloc((size_t)NGRAPH * DIM * sizeof(float));
    float*    t1     = (float*)   alloc((size_t)NGRAPH * DIM * sizeof(float));

    const int gemmBlocks = (NNODES + 127) / 128;   // 782

    // ---- bucketed CSR build ----
    k_zero_int <<<(NSETS * NBUCK + 255) / 256, 256, 0, stream>>>(bcnt, NSETS * NBUCK);
    k_bhist    <<<EBLOCKS, 256, 0, stream>>>(dst, bcnt);
    k_bscan    <<<1, 1024, 0, stream>>>(bcnt, boff, cur, bbase);
    k_bscatter <<<EBLOCKS, 256, 0, stream>>>(src, dst, cur, tmp);
    k_build    <<<(NNODES + 127) / 128, 256, 0, stream>>>(tmp, bcnt, boff, bbase,
                                                          row_off, inv, col);

    // ---- encoder (fp32 x -> bf16 h) ----
    gemm_mfma<0,1><<<gemmBlocks, 256, 0, stream>>>(x,    enc_W1, enc_b1, nullptr, bufA, NNODES);
    gemm_mfma<0,0><<<gemmBlocks, 256, 0, stream>>>(bufA, enc_W2, enc_b2, nullptr, bufB, NNODES);

    // ---- GCN layers ----
    for (int l = 0; l < 3; ++l) {
        gemm_mfma<1,0><<<gemmBlocks, 256, 0, stream>>>(bufB, gcn_W + (size_t)l * DIM * DIM,
                                                       nullptr, inv, bufA, NNODES);
        k_agg<<<NNODES / 4, 256, 0, stream>>>(bufA, row_off, col, inv,
                                              gcn_b + (size_t)l * DIM, bufB);
    }

    // ---- pool + decoder ----
    k_pool<<<NGRAPH, 128, 0, stream>>>(bufB, batch, pooled);
    gemm128_f32<<<(NGRAPH + 127) / 128, 256, 0, stream>>>(pooled, dec_W1, dec_b1, t1, NGRAPH);
    k_dec2<<<(NGRAPH * OUTD + 255) / 256, 256, 0, stream>>>(t1, dec_W2, dec_b2, out);
}

// Round 4
// 536.235 us; speedup vs baseline: 1.9023x; 1.2575x over previous
//
#include <hip/hip_runtime.h>

#define NNODES 100000
#define NEDGES 1600000
#define DIM    128
#define OUTD   32
#define NGRAPH 512
#define LDA    136   // padded LDS stride (bf16 elems)

#define NBUCK2  256                          // coarse buckets: dst >> 9
#define BSHIFT  9
#define CAP     12288                        // per-bucket region capacity (mean 8163)
#define EPB2    8192
#define SBLOCKS ((NEDGES + EPB2 - 1) / EPB2) // 196
#define NBUILD  ((NNODES + 511) / 512)       // 196

using bf16x8 = __attribute__((ext_vector_type(8))) short;
using f32x4  = __attribute__((ext_vector_type(4))) float;

__device__ __forceinline__ short f2bf(float f) {
    unsigned u = __float_as_uint(f);
    unsigned r = (u + 0x7fff + ((u >> 16) & 1)) >> 16;   // RNE
    return (short)r;
}
__device__ __forceinline__ float bf2f(short s) {
    return __uint_as_float(((unsigned)(unsigned short)s) << 16);
}
__device__ __forceinline__ float bf2f_lo(unsigned u) { return __uint_as_float(u << 16); }
__device__ __forceinline__ float bf2f_hi(unsigned u) { return __uint_as_float(u & 0xffff0000u); }

// ============================================================
// Weight pre-transpose: WT[mat][n][k] = bf16(W[mat][k][n])
// ============================================================
__global__ __launch_bounds__(256) void k_prepW(
    const float* __restrict__ W, short* __restrict__ WT, int nmat)
{
    int idx = blockIdx.x * 256 + threadIdx.x;
    if (idx >= nmat * DIM * DIM) return;
    int mat = idx >> 14;
    int rem = idx & 16383;
    int k = rem >> 7, n = rem & 127;
    WT[(size_t)mat * 16384 + n * DIM + k] = f2bf(W[(size_t)mat * 16384 + k * DIM + n]);
}

// ============================================================
// bf16 MFMA GEMM: C[M,128](bf16) = epi(A[M,128] @ W), W given as bf16 W^T
// MODE 0: relu(acc + bias[col]) ; MODE 1: acc * inv[row]
// AFP32: A is fp32 (converted during staging), else bf16
// ============================================================
template<int MODE, int AFP32>
__global__ __launch_bounds__(256) void gemm_mfma(
    const void* __restrict__ Av, const short* __restrict__ WT,
    const float* __restrict__ bias, const float* __restrict__ inv,
    short* __restrict__ C, int M)
{
    __shared__ short As[128 * LDA];
    __shared__ short Bs[128 * LDA];

    const int tid = threadIdx.x;
    const int m0  = blockIdx.x * 128;

    if (AFP32) {
        const float* A = (const float*)Av;
        #pragma unroll
        for (int i = 0; i < 8; ++i) {
            int idx = tid + i * 256;
            int row = idx >> 4, kg = (idx & 15) << 3;
            int r = min(m0 + row, M - 1);
            const float4* sp = (const float4*)(A + (size_t)r * DIM + kg);
            float4 f0 = sp[0], f1 = sp[1];
            short t8[8] = { f2bf(f0.x), f2bf(f0.y), f2bf(f0.z), f2bf(f0.w),
                            f2bf(f1.x), f2bf(f1.y), f2bf(f1.z), f2bf(f1.w) };
            *(bf16x8*)&As[row * LDA + kg] = *(bf16x8*)t8;
        }
    } else {
        const short* A = (const short*)Av;
        #pragma unroll
        for (int i = 0; i < 8; ++i) {
            int idx = tid + i * 256;
            int row = idx >> 4, kg = (idx & 15) << 3;
            int r = min(m0 + row, M - 1);
            *(bf16x8*)&As[row * LDA + kg] = *(const bf16x8*)(A + (size_t)r * DIM + kg);
        }
    }
    #pragma unroll
    for (int i = 0; i < 8; ++i) {
        int idx = tid + i * 256;
        int n = idx >> 4, kg = (idx & 15) << 3;
        *(bf16x8*)&Bs[n * LDA + kg] = *(const bf16x8*)(WT + n * DIM + kg);
    }
    __syncthreads();

    const int wave = tid >> 6, lane = tid & 63;
    const int ml = lane & 15, quad = lane >> 4;
    const int w32 = wave * 32;

    f32x4 acc[2][8] = {};
    #pragma unroll
    for (int kk = 0; kk < 4; ++kk) {
        const int k0 = kk * 32 + quad * 8;
        bf16x8 a0 = *(bf16x8*)&As[(w32 + ml) * LDA + k0];
        bf16x8 a1 = *(bf16x8*)&As[(w32 + 16 + ml) * LDA + k0];
        #pragma unroll
        for (int ni = 0; ni < 8; ++ni) {
            bf16x8 b = *(bf16x8*)&Bs[(ni * 16 + ml) * LDA + k0];
            acc[0][ni] = __builtin_amdgcn_mfma_f32_16x16x32_bf16(a0, b, acc[0][ni], 0, 0, 0);
            acc[1][ni] = __builtin_amdgcn_mfma_f32_16x16x32_bf16(a1, b, acc[1][ni], 0, 0, 0);
        }
    }
    __syncthreads();

    short* Cs = As;
    #pragma unroll
    for (int mi = 0; mi < 2; ++mi) {
        #pragma unroll
        for (int ni = 0; ni < 8; ++ni) {
            const int colc = ni * 16 + ml;
            #pragma unroll
            for (int r = 0; r < 4; ++r) {
                const int row = w32 + mi * 16 + quad * 4 + r;
                float v = acc[mi][ni][r];
                if (MODE == 0) {
                    v = fmaxf(v + bias[colc], 0.f);
                } else {
                    int gr = min(m0 + row, M - 1);
                    v *= inv[gr];
                }
                Cs[row * LDA + colc] = f2bf(v);
            }
        }
    }
    __syncthreads();
    #pragma unroll
    for (int i = 0; i < 8; ++i) {
        int idx = tid + i * 256;
        int row = idx >> 4, cg = (idx & 15) << 3;
        int gr = m0 + row;
        if (gr < M)
            *(bf16x8*)(C + (size_t)gr * DIM + cg) = *(bf16x8*)&Cs[row * LDA + cg];
    }
}

// ============================================================
// fp32 GEMM for the tiny decoder (M=512)
// ============================================================
__global__ __launch_bounds__(256) void gemm128_f32(
    const float* __restrict__ A, const float* __restrict__ W,
    const float* __restrict__ bias, float* __restrict__ C, int M)
{
    __shared__ float As[16][132];
    __shared__ float Bs[16][132];

    const int tid = threadIdx.x;
    const int m0  = blockIdx.x * 128;
    const int tx  = tid & 15;
    const int ty  = tid >> 4;
    const int ar = tid >> 2;
    const int ac = (tid & 3) << 2;
    const int br = tid >> 5;
    const int bc = (tid & 31) << 2;

    float acc[8][8];
    #pragma unroll
    for (int i = 0; i < 8; ++i)
        #pragma unroll
        for (int j = 0; j < 8; ++j) acc[i][j] = 0.f;

    for (int kt = 0; kt < 8; ++kt) {
        const int k0 = kt << 4;
        const int r0 = min(m0 + ar,      M - 1);
        const int r1 = min(m0 + ar + 64, M - 1);
        float4 a0 = *(const float4*)(A + (size_t)r0 * DIM + k0 + ac);
        float4 a1 = *(const float4*)(A + (size_t)r1 * DIM + k0 + ac);
        float4 b0 = *(const float4*)(W + (size_t)(k0 + br)     * DIM + bc);
        float4 b1 = *(const float4*)(W + (size_t)(k0 + br + 8) * DIM + bc);

        __syncthreads();
        As[ac + 0][ar] = a0.x; As[ac + 1][ar] = a0.y;
        As[ac + 2][ar] = a0.z; As[ac + 3][ar] = a0.w;
        As[ac + 0][ar + 64] = a1.x; As[ac + 1][ar + 64] = a1.y;
        As[ac + 2][ar + 64] = a1.z; As[ac + 3][ar + 64] = a1.w;
        *(float4*)&Bs[br][bc]     = b0;
        *(float4*)&Bs[br + 8][bc] = b1;
        __syncthreads();

        #pragma unroll
        for (int kk = 0; kk < 16; ++kk) {
            float4 fa0 = *(const float4*)&As[kk][ty * 8];
            float4 fa1 = *(const float4*)&As[kk][ty * 8 + 4];
            float4 fb0 = *(const float4*)&Bs[kk][tx * 8];
            float4 fb1 = *(const float4*)&Bs[kk][tx * 8 + 4];
            float av[8] = {fa0.x, fa0.y, fa0.z, fa0.w, fa1.x, fa1.y, fa1.z, fa1.w};
            float bv[8] = {fb0.x, fb0.y, fb0.z, fb0.w, fb1.x, fb1.y, fb1.z, fb1.w};
            #pragma unroll
            for (int i = 0; i < 8; ++i)
                #pragma unroll
                for (int j = 0; j < 8; ++j)
                    acc[i][j] = fmaf(av[i], bv[j], acc[i][j]);
        }
    }

    float4 bb0 = *(const float4*)(bias + tx * 8);
    float4 bb1 = *(const float4*)(bias + tx * 8 + 4);
    float bcol[8] = {bb0.x, bb0.y, bb0.z, bb0.w, bb1.x, bb1.y, bb1.z, bb1.w};

    #pragma unroll
    for (int i = 0; i < 8; ++i) {
        const int r = m0 + ty * 8 + i;
        if (r >= M) break;
        float v[8];
        #pragma unroll
        for (int j = 0; j < 8; ++j) v[j] = fmaxf(acc[i][j] + bcol[j], 0.f);
        *(float4*)(C + (size_t)r * DIM + tx * 8)     = make_float4(v[0], v[1], v[2], v[3]);
        *(float4*)(C + (size_t)r * DIM + tx * 8 + 4) = make_float4(v[4], v[5], v[6], v[7]);
    }
}

// ============================================================
// CSR build: block-local reservation scatter + per-bucket build
// ============================================================
__global__ __launch_bounds__(256) void k_initcur(int* __restrict__ gcur) {
    int i = blockIdx.x * 256 + threadIdx.x;
    if (i < NBUCK2) gcur[i] = i * CAP;
}

__global__ __launch_bounds__(512) void k_scatter(
    const int* __restrict__ src, const int* __restrict__ dst,
    int* __restrict__ gcur, unsigned* __restrict__ tmp)
{
    __shared__ unsigned short rnk[EPB2];
    __shared__ int h[NBUCK2];
    __shared__ int gbase[NBUCK2];
    const int tid  = threadIdx.x;
    const int base = blockIdx.x * EPB2;
    if (tid < NBUCK2) h[tid] = 0;
    __syncthreads();
    #pragma unroll
    for (int it = 0; it < EPB2 / 512; ++it) {
        int e = base + it * 512 + tid;
        if (e < NEDGES) {
            int b = dst[e] >> BSHIFT;
            rnk[it * 512 + tid] = (unsigned short)atomicAdd(&h[b], 1);
        }
    }
    __syncthreads();
    if (tid < NBUCK2 && h[tid] > 0)
        gbase[tid] = atomicAdd(&gcur[tid], h[tid]);
    __syncthreads();
    #pragma unroll
    for (int it = 0; it < EPB2 / 512; ++it) {
        int e = base + it * 512 + tid;
        if (e < NEDGES) {
            int d = dst[e], sv = src[e];
            int b = d >> BSHIFT;
            int pos = gbase[b] + rnk[it * 512 + tid];
            if (pos < (b + 1) * CAP)   // overflow guard (never fires w/ uniform dst)
                tmp[pos] = (unsigned)sv | ((unsigned)(d & 511) << 17);
        }
    }
}

__global__ __launch_bounds__(512) void k_build(
    const unsigned* __restrict__ tmp, const int* __restrict__ gcur,
    int* __restrict__ row_off, int* __restrict__ cntA,
    float* __restrict__ inv, int* __restrict__ col)
{
    __shared__ int hist[512], sc[512], lcur[512];
    const int tid   = threadIdx.x;
    const int b     = blockIdx.x;
    const int tbase = b * CAP;
    const int cnt_b = min(gcur[b] - tbase, CAP);
    hist[tid] = 0;
    __syncthreads();
    for (int i = tid; i < cnt_b; i += 512)
        atomicAdd(&hist[(tmp[tbase + i] >> 17) & 511], 1);
    __syncthreads();
    const int hv = hist[tid];
    sc[tid] = hv;
    __syncthreads();
    for (int off = 1; off < 512; off <<= 1) {
        int t = (tid >= off) ? sc[tid - off] : 0;
        __syncthreads();
        sc[tid] += t;
        __syncthreads();
    }
    const int start = tbase + sc[tid] - hv;
    lcur[tid] = start;
    const int node = b * 512 + tid;
    if (node < NNODES) {
        row_off[node] = start;
        cntA[node]    = hv;
        inv[node]     = rsqrtf((float)hv + 1.0f);
    }
    __syncthreads();
    for (int i = tid; i < cnt_b; i += 512) {
        unsigned t = tmp[tbase + i];
        int pos = atomicAdd(&lcur[(t >> 17) & 511], 1);
        col[pos] = (int)(t & 0x1FFFFu);
    }
}

// ============================================================
// Aggregation (bf16): h_out[n] = relu(inv[n]*(hw'[n] + sum hw'[src]) + b)
// ============================================================
__global__ __launch_bounds__(256) void k_agg(
    const short* __restrict__ hwp, const int* __restrict__ row_off,
    const int* __restrict__ cntA, const int* __restrict__ col,
    const float* __restrict__ inv, const float* __restrict__ bias,
    short* __restrict__ hout)
{
    const int node = blockIdx.x * 4 + (threadIdx.x >> 6);
    const int lane = threadIdx.x & 63;
    if (node >= NNODES) return;

    const unsigned* hp = (const unsigned*)hwp;
    unsigned us = hp[(size_t)node * 64 + lane];
    float ax = bf2f_lo(us), ay = bf2f_hi(us);

    const int s = row_off[node];
    const int e = s + cntA[node];
    int j = s;
    for (; j + 3 < e; j += 4) {
        int u0 = col[j], u1 = col[j + 1], u2 = col[j + 2], u3 = col[j + 3];
        unsigned v0 = hp[(size_t)u0 * 64 + lane];
        unsigned v1 = hp[(size_t)u1 * 64 + lane];
        unsigned v2 = hp[(size_t)u2 * 64 + lane];
        unsigned v3 = hp[(size_t)u3 * 64 + lane];
        ax += bf2f_lo(v0) + bf2f_lo(v1) + bf2f_lo(v2) + bf2f_lo(v3);
        ay += bf2f_hi(v0) + bf2f_hi(v1) + bf2f_hi(v2) + bf2f_hi(v3);
    }
    for (; j < e; ++j) {
        unsigned v = hp[(size_t)col[j] * 64 + lane];
        ax += bf2f_lo(v); ay += bf2f_hi(v);
    }
    const float scv = inv[node];
    const float2 b = ((const float2*)bias)[lane];
    float ox = fmaxf(fmaf(ax, scv, b.x), 0.f);
    float oy = fmaxf(fmaf(ay, scv, b.y), 0.f);
    unsigned lo = (unsigned)(unsigned short)f2bf(ox);
    unsigned hi = (unsigned)(unsigned short)f2bf(oy);
    ((unsigned*)hout)[(size_t)node * 64 + lane] = lo | (hi << 16);
}

// ============================================================
// Global add pool (bf16 in, fp32 out)
// ============================================================
__device__ int lbound(const int* __restrict__ a, int n, int v) {
    int lo = 0, hi = n;
    while (lo < hi) { int mid = (lo + hi) >> 1; if (a[mid] < v) lo = mid + 1; else hi = mid; }
    return lo;
}

__global__ __launch_bounds__(128) void k_pool(
    const short* __restrict__ h, const int* __restrict__ batch,
    float* __restrict__ pooled)
{
    __shared__ int se[2];
    const int g = blockIdx.x;
    if (threadIdx.x == 0) se[0] = lbound(batch, NNODES, g);
    if (threadIdx.x == 1) se[1] = lbound(batch, NNODES, g + 1);
    __syncthreads();
    const int s = se[0], e = se[1];
    const int f = threadIdx.x;
    float acc = 0.f;
    for (int n = s; n < e; ++n) acc += bf2f(h[(size_t)n * DIM + f]);
    pooled[(size_t)g * DIM + f] = acc;
}

// ============================================================
__global__ __launch_bounds__(256) void k_dec2(
    const float* __restrict__ t1, const float* __restrict__ W2,
    const float* __restrict__ b2, float* __restrict__ out)
{
    int idx = blockIdx.x * 256 + threadIdx.x;
    if (idx >= NGRAPH * OUTD) return;
    int r = idx >> 5, c = idx & 31;
    float acc = b2[c];
    #pragma unroll 8
    for (int k = 0; k < DIM; ++k)
        acc = fmaf(t1[(size_t)r * DIM + k], W2[(size_t)k * OUTD + c], acc);
    out[idx] = acc;
}

// ============================================================
extern "C" void kernel_launch(void* const* d_in, const int* in_sizes, int n_in,
                              void* d_out, int out_size, void* d_ws, size_t ws_size,
                              hipStream_t stream)
{
    const float* x      = (const float*)d_in[0];
    const int*   ei     = (const int*)d_in[1];
    const int*   batch  = (const int*)d_in[2];
    const float* enc_W1 = (const float*)d_in[3];
    const float* enc_b1 = (const float*)d_in[4];
    const float* enc_W2 = (const float*)d_in[5];
    const float* enc_b2 = (const float*)d_in[6];
    const float* gcn_W  = (const float*)d_in[7];
    const float* gcn_b  = (const float*)d_in[8];
    const float* dec_W1 = (const float*)d_in[9];
    const float* dec_b1 = (const float*)d_in[10];
    const float* dec_W2 = (const float*)d_in[11];
    const float* dec_b2 = (const float*)d_in[12];
    float* out = (float*)d_out;

    const int* src = ei;
    const int* dst = ei + NEDGES;

    char* p = (char*)d_ws;
    auto alloc = [&](size_t bytes) -> void* {
        void* r = (void*)p;
        p += (bytes + 255) & ~(size_t)255;
        return r;
    };
    short*    bufA   = (short*)   alloc((size_t)NNODES * DIM * sizeof(short));
    short*    bufB   = (short*)   alloc((size_t)NNODES * DIM * sizeof(short));
    float*    inv    = (float*)   alloc((size_t)NNODES * sizeof(float));
    int*      row_off= (int*)     alloc((size_t)NNODES * sizeof(int));
    int*      cntA   = (int*)     alloc((size_t)NNODES * sizeof(int));
    int*      col    = (int*)     alloc((size_t)NBUCK2 * CAP * sizeof(int));
    unsigned* tmp    = (unsigned*)alloc((size_t)NBUCK2 * CAP * sizeof(unsigned));
    int*      gcur   = (int*)     alloc((size_t)NBUCK2 * sizeof(int));
    short*    WT     = (short*)   alloc((size_t)5 * DIM * DIM * sizeof(short));
    float*    pooled = (float*)   alloc((size_t)NGRAPH * DIM * sizeof(float));
    float*    t1     = (float*)   alloc((size_t)NGRAPH * DIM * sizeof(float));

    const int gemmBlocks = (NNODES + 127) / 128;   // 782

    // ---- CSR build ----
    k_initcur<<<1, 256, 0, stream>>>(gcur);
    k_scatter<<<SBLOCKS, 512, 0, stream>>>(src, dst, gcur, tmp);
    k_build  <<<NBUILD, 512, 0, stream>>>(tmp, gcur, row_off, cntA, inv, col);

    // ---- weight pre-transpose (bf16 W^T) ----
    k_prepW<<<(2 * DIM * DIM + 255) / 256, 256, 0, stream>>>(enc_W1, WT, 1);
    k_prepW<<<(DIM * DIM + 255) / 256, 256, 0, stream>>>(enc_W2, WT + 16384, 1);
    k_prepW<<<(3 * DIM * DIM + 255) / 256, 256, 0, stream>>>(gcn_W, WT + 2 * 16384, 3);

    // ---- encoder (fp32 x -> bf16 h) ----
    gemm_mfma<0,1><<<gemmBlocks, 256, 0, stream>>>(x,    WT,          enc_b1, nullptr, bufA, NNODES);
    gemm_mfma<0,0><<<gemmBlocks, 256, 0, stream>>>(bufA, WT + 16384,  enc_b2, nullptr, bufB, NNODES);

    // ---- GCN layers ----
    for (int l = 0; l < 3; ++l) {
        gemm_mfma<1,0><<<gemmBlocks, 256, 0, stream>>>(bufB, WT + (2 + l) * 16384,
                                                       nullptr, inv, bufA, NNODES);
        k_agg<<<NNODES / 4, 256, 0, stream>>>(bufA, row_off, cntA, col, inv,
                                              gcn_b + (size_t)l * DIM, bufB);
    }

    // ---- pool + decoder ----
    k_pool<<<NGRAPH, 128, 0, stream>>>(bufB, batch, pooled);
    gemm128_f32<<<(NGRAPH + 127) / 128, 256, 0, stream>>>(pooled, dec_W1, dec_b1, t1, NGRAPH);
    k_dec2<<<(NGRAPH * OUTD + 255) / 256, 256, 0, stream>>>(t1, dec_W2, dec_b2, out);
}